// Round 1
// baseline (3716.248 us; speedup 1.0000x reference)
//
#include <hip/hip_runtime.h>
#include <math.h>

// ---- problem constants ----
#define BATCH   16
#define SEQ     4096
#define DMODEL  64
#define DINNER  128
#define DSTATE  32
#define NHEADS  2
#define HEADDIM 64
#define CONVDIM 192            // DINNER + 2*DSTATE
#define PROJ    322            // 2*DINNER + 2*DSTATE + NHEADS
#define QC      64             // chunk length for SSD scan
#define NCHUNK  (SEQ/QC)       // 64
#define BL      (BATCH*SEQ)    // 65536 rows

// ---- static device scratch (avoids relying on ws_size) ----
__device__ float g_zx  [(size_t)BL*PROJ];      // in_proj output (z | xBC | dt_raw)
__device__ float g_xbcc[(size_t)BL*CONVDIM];   // conv+silu output (x | B | C)
__device__ float g_dt  [BATCH*NHEADS*SEQ];     // softplus(dt)
__device__ float g_cum [BATCH*NHEADS*SEQ];     // within-chunk inclusive cumsum of dt*A
__device__ float g_ctot[BATCH*NHEADS*NCHUNK];  // per-chunk total log-decay
__device__ float g_S   [BATCH*NHEADS*NCHUNK*DSTATE*HEADDIM]; // chunk state contributions
__device__ float g_H   [BATCH*NHEADS*NCHUNK*DSTATE*HEADDIM]; // state at chunk start
__device__ float g_y   [(size_t)BL*DINNER];    // y buffer (intra -> full -> gated)
__device__ float g_ping0[(size_t)BL*DMODEL];
__device__ float g_ping1[(size_t)BL*DMODEL];

// ---- K1: in_proj GEMM  (BLx64) @ (64x322) -> g_zx ----
__global__ __launch_bounds__(256) void k_inproj(const float* __restrict__ xext, int sel,
                                                const float* __restrict__ Win) {
  __shared__ float xs[64][64];
  const float* __restrict__ X = (sel==0) ? xext : (sel==1 ? g_ping0 : g_ping1);
  const int row0 = blockIdx.x * 64;
  const int tid  = threadIdx.x;
#pragma unroll
  for (int j=0;j<16;j++){ int e = tid + j*256; int r = e>>6, c2 = e&63;
    xs[r][c2] = X[(size_t)(row0+r)*DMODEL + c2]; }
  __syncthreads();
  const int c = blockIdx.y*256 + tid;
  if (c < PROJ) {
    float w[64];
#pragma unroll
    for (int k=0;k<64;k++) w[k] = Win[k*PROJ + c];
#pragma unroll 4
    for (int r=0;r<64;r++){
      float acc = 0.f;
#pragma unroll
      for (int k=0;k<64;k++) acc = fmaf(xs[r][k], w[k], acc);
      g_zx[(size_t)(row0+r)*PROJ + c] = acc;
    }
  }
}

// ---- K2: dt softplus + within-chunk cumsum of dt*A ----
__global__ __launch_bounds__(64) void k_dtcum(const float* __restrict__ dt_bias,
                                              const float* __restrict__ A_log) {
  const int bx = blockIdx.x;                 // 16*2*64 = 2048 blocks
  const int b = bx >> 7, h = (bx >> 6) & 1, ch = bx & 63;
  const int lane = threadIdx.x;
  const int t = ch*QC + lane;
  float xv  = g_zx[(size_t)(b*SEQ + t)*PROJ + (DINNER+CONVDIM) + h] + dt_bias[h];
  float dtv = (xv > 20.f) ? xv : log1pf(expf(xv));
  float A   = -expf(A_log[h]);
  float cum = dtv * A;
#pragma unroll
  for (int off=1; off<64; off<<=1){
    float v = __shfl_up(cum, off);
    if (lane >= off) cum += v;
  }
  const int base = (b*NHEADS + h)*SEQ + t;
  g_dt [base] = dtv;
  g_cum[base] = cum;
  if (lane == 63) g_ctot[(b*NHEADS+h)*NCHUNK + ch] = cum;
}

// ---- K3: depthwise causal conv(4) + bias + SiLU on xBC columns ----
__global__ __launch_bounds__(256) void k_conv(const float* __restrict__ conv_w,
                                              const float* __restrict__ conv_b) {
  const int idx = blockIdx.x*256 + threadIdx.x;   // < BL*CONVDIM
  const int c = idx % CONVDIM;
  const int r = idx / CONVDIM;
  const int t = r & (SEQ-1);
  float acc = conv_b[c];
#pragma unroll
  for (int k=0;k<4;k++){
    int tt = t - 3 + k;
    if (tt >= 0) acc = fmaf(conv_w[c*4+k], g_zx[(size_t)(r-3+k)*PROJ + DINNER + c], acc);
  }
  g_xbcc[(size_t)r*CONVDIM + c] = acc / (1.f + expf(-acc));
}

// ---- K4: per-(b,h,chunk): G=(C B^T)*mask, Y_intra=G@X, S=chunk state ----
__global__ __launch_bounds__(256) void k_chunkA() {
  __shared__ float Xs[QC][HEADDIM];        // 16 KB
  __shared__ float Bs[QC][DSTATE+1];       // padded: kills 64-way bank conflict
  __shared__ float Cs[QC][DSTATE+1];
  __shared__ float Gs[QC][QC];             // 16 KB
  __shared__ float cuml[QC], dtl[QC], ew[QC];
  const int bx = blockIdx.x; const int b = bx>>7, h=(bx>>6)&1, ch=bx&63;
  const int tid = threadIdx.x;
  const size_t row0 = (size_t)b*SEQ + (size_t)ch*QC;
#pragma unroll
  for (int j=0;j<16;j++){ int e=tid+j*256; int s=e>>6, p=e&63;
    Xs[s][p] = g_xbcc[(row0+s)*CONVDIM + h*HEADDIM + p]; }
#pragma unroll
  for (int j=0;j<8;j++){ int e=tid+j*256; int s=e>>5, n=e&31;
    Bs[s][n] = g_xbcc[(row0+s)*CONVDIM + DINNER + n];
    Cs[s][n] = g_xbcc[(row0+s)*CONVDIM + DINNER + DSTATE + n]; }
  if (tid < QC){
    int base = (b*NHEADS+h)*SEQ + ch*QC + tid;
    cuml[tid] = g_cum[base];
    dtl [tid] = g_dt [base];
  }
  __syncthreads();
  if (tid < QC) ew[tid] = expf(cuml[QC-1]-cuml[tid]) * dtl[tid];
  const int s_ = tid & 63, tg = tid >> 6;
#pragma unroll 2
  for (int i=0;i<16;i++){
    int t = tg*16 + i;
    float g = 0.f;
    if (s_ <= t){
      float acc = 0.f;
#pragma unroll
      for (int n=0;n<DSTATE;n++) acc = fmaf(Cs[t][n], Bs[s_][n], acc);
      g = expf(cuml[t]-cuml[s_]) * dtl[s_] * acc;
    }
    Gs[t][s_] = g;
  }
  __syncthreads();
  const int p_ = s_;
#pragma unroll 2
  for (int i=0;i<16;i++){
    int t = tg*16 + i;
    float acc = 0.f;
#pragma unroll
    for (int s=0;s<QC;s++) acc = fmaf(Gs[t][s], Xs[s][p_], acc);
    g_y[(row0+t)*DINNER + h*HEADDIM + p_] = acc;
  }
  const size_t sbase = (size_t)((b*NHEADS+h)*NCHUNK + ch) * (DSTATE*HEADDIM);
#pragma unroll 2
  for (int i=0;i<8;i++){
    int n = tg*8 + i;
    float acc = 0.f;
#pragma unroll
    for (int s=0;s<QC;s++) acc = fmaf(ew[s]*Bs[s][n], Xs[s][p_], acc);
    g_S[sbase + n*HEADDIM + p_] = acc;
  }
}

// ---- K5: sequential-over-chunks state scan (parallel over b,h,n,p) ----
__global__ __launch_bounds__(256) void k_chunkScan() {
  const int idx = blockIdx.x*256 + threadIdx.x;   // < 65536
  const int np = idx & 2047;
  const int bh = idx >> 11;
  float h = 0.f;
  const size_t base = (size_t)bh*NCHUNK*2048 + np;
#pragma unroll 1
  for (int k=0;k<NCHUNK;k++){
    g_H[base + (size_t)k*2048] = h;                 // state at START of chunk k
    h = h*expf(g_ctot[bh*NCHUNK+k]) + g_S[base + (size_t)k*2048];
  }
}

// ---- K6: add inter-chunk output + D*x, then gate with silu(z) ----
__global__ __launch_bounds__(256) void k_chunkC(const float* __restrict__ Dp) {
  __shared__ float H2[NHEADS][DSTATE*HEADDIM];   // 16 KB
  __shared__ float Cl[QC][DSTATE+1];
  __shared__ float cum2[NHEADS][QC];
  const int bx = blockIdx.x; const int b = bx>>6, ch = bx&63;
  const int tid = threadIdx.x;
  const size_t row0 = (size_t)b*SEQ + (size_t)ch*QC;
#pragma unroll
  for (int j=0;j<16;j++){ int e=tid+j*256; int h_=e>>11, rem=e&2047;
    H2[h_][rem] = g_H[(size_t)((b*NHEADS+h_)*NCHUNK + ch)*2048 + rem]; }
#pragma unroll
  for (int j=0;j<8;j++){ int e=tid+j*256; int s=e>>5, n=e&31;
    Cl[s][n] = g_xbcc[(row0+s)*CONVDIM + DINNER + DSTATE + n]; }
  if (tid < 128){ int h_=tid>>6, s=tid&63;
    cum2[h_][s] = g_cum[(b*NHEADS+h_)*SEQ + ch*QC + s]; }
  __syncthreads();
  const float dp0 = Dp[0], dp1 = Dp[1];
#pragma unroll 1
  for (int e=tid; e<QC*DINNER; e+=256){
    int tq = e>>7, hp = e&127;
    int h_ = hp>>6, p = hp&63;
    size_t row = row0 + tq;
    float acc = 0.f;
#pragma unroll
    for (int n=0;n<DSTATE;n++) acc = fmaf(Cl[tq][n], H2[h_][n*64+p], acc);
    float xval = g_xbcc[row*CONVDIM + hp];
    float yv = g_y[row*DINNER + hp] + expf(cum2[h_][tq])*acc + (h_?dp1:dp0)*xval;
    float zv = g_zx[row*PROJ + hp];
    yv *= zv / (1.f + expf(-zv));
    g_y[row*DINNER + hp] = yv;
  }
}

// ---- K7: RMSNorm + out GEMM (128->64); one wave per row ----
__global__ __launch_bounds__(256) void k_outproj(const float* __restrict__ normw,
                                                 const float* __restrict__ Wout,
                                                 float* __restrict__ dout, int dsel) {
  __shared__ float Wl[DINNER*DMODEL];  // 32 KB
  __shared__ float yn[4][DINNER];
  float* __restrict__ out = (dsel==0) ? g_ping0 : (dsel==1 ? g_ping1 : dout);
  const int tid = threadIdx.x;
#pragma unroll
  for (int j=0;j<32;j++){ int e=tid+j*256; Wl[e] = Wout[e]; }
  const int wave = tid>>6, lane = tid&63;
  const size_t row = (size_t)blockIdx.x*4 + wave;
  const float* __restrict__ yr = g_y + row*DINNER;
  float v0 = yr[lane], v1 = yr[lane+64];
  float ss = v0*v0 + v1*v1;
#pragma unroll
  for (int off=32; off>=1; off>>=1) ss += __shfl_xor(ss, off);
  float sc = rsqrtf(ss*(1.f/128.f) + 1e-5f);
  yn[wave][lane]    = v0*sc*normw[lane];
  yn[wave][lane+64] = v1*sc*normw[lane+64];
  __syncthreads();
  float acc = 0.f;
#pragma unroll 4
  for (int i=0;i<DINNER;i++) acc = fmaf(yn[wave][i], Wl[i*64+lane], acc);
  out[row*DMODEL + lane] = acc;
}

extern "C" void kernel_launch(void* const* d_in, const int* in_sizes, int n_in,
                              void* d_out, int out_size, void* d_ws, size_t ws_size,
                              hipStream_t stream) {
  (void)in_sizes; (void)n_in; (void)d_ws; (void)ws_size; (void)out_size;
  const float* x       = (const float*)d_in[0];
  const float* Win     = (const float*)d_in[1];
  const float* conv_w  = (const float*)d_in[2];
  const float* conv_b  = (const float*)d_in[3];
  const float* dt_bias = (const float*)d_in[4];
  const float* A_log   = (const float*)d_in[5];
  const float* Dp      = (const float*)d_in[6];
  const float* norm_w  = (const float*)d_in[7];
  const float* Wout    = (const float*)d_in[8];

  for (int layer = 0; layer < 8; ++layer) {
    const int insel = (layer==0) ? 0 : ((((layer-1)&1)==0) ? 1 : 2);
    const int dsel  = (layer==7) ? 2 : ((layer&1)==0 ? 0 : 1);

    k_inproj<<<dim3(BL/64, 2), 256, 0, stream>>>(x, insel, Win + (size_t)layer*DMODEL*PROJ);
    k_dtcum<<<BATCH*NHEADS*NCHUNK, 64, 0, stream>>>(dt_bias + layer*NHEADS, A_log + layer*NHEADS);
    k_conv<<<(BL*CONVDIM)/256, 256, 0, stream>>>(conv_w + (size_t)layer*CONVDIM*4, conv_b + (size_t)layer*CONVDIM);
    k_chunkA<<<BATCH*NHEADS*NCHUNK, 256, 0, stream>>>();
    k_chunkScan<<<(BATCH*NHEADS*DSTATE*HEADDIM)/256, 256, 0, stream>>>();
    k_chunkC<<<BATCH*NCHUNK, 256, 0, stream>>>(Dp + layer*NHEADS);
    k_outproj<<<BL/4, 256, 0, stream>>>(norm_w + layer*DINNER, Wout + (size_t)layer*DINNER*DMODEL,
                                        (float*)d_out, dsel);
  }
}

// Round 2
// 2544.377 us; speedup vs baseline: 1.4606x; 1.4606x over previous
//
#include <hip/hip_runtime.h>
#include <math.h>

// ---- problem constants ----
#define BATCH   16
#define SEQ     4096
#define DMODEL  64
#define DINNER  128
#define DSTATE  32
#define NHEADS  2
#define HEADDIM 64
#define CONVDIM 192            // DINNER + 2*DSTATE
#define PROJ    322            // 2*DINNER + 2*DSTATE + NHEADS
#define QC      64             // chunk length for SSD scan
#define NCHUNK  (SEQ/QC)       // 64
#define BL      (BATCH*SEQ)    // 65536 rows

typedef __attribute__((ext_vector_type(8))) short short8;   // 8 bf16 (4 VGPRs)
typedef __attribute__((ext_vector_type(4))) float f32x4;    // MFMA C/D

__device__ inline unsigned short f2b(float f){
  union { float f; unsigned u; } v; v.f = f;
  unsigned r = v.u + 0x7FFF + ((v.u >> 16) & 1);   // round-to-nearest-even
  return (unsigned short)(r >> 16);
}

// ---- static device scratch ----
__device__ float g_zx  [(size_t)BL*PROJ];      // in_proj output (z | xBC | dt_raw)
__device__ float g_xbcc[(size_t)BL*CONVDIM];   // conv+silu output (x | B | C)
__device__ float g_dt  [BATCH*NHEADS*SEQ];     // softplus(dt)
__device__ float g_cum [BATCH*NHEADS*SEQ];     // within-chunk inclusive cumsum of dt*A
__device__ float g_ctot[BATCH*NHEADS*NCHUNK];  // per-chunk total log-decay
__device__ float g_S   [BATCH*NHEADS*NCHUNK*DSTATE*HEADDIM]; // chunk state contributions
__device__ float g_H   [BATCH*NHEADS*NCHUNK*DSTATE*HEADDIM]; // state at chunk start
__device__ float g_y   [(size_t)BL*DINNER];    // y buffer (intra -> full -> gated)
__device__ float g_ping0[(size_t)BL*DMODEL];
__device__ float g_ping1[(size_t)BL*DMODEL];

// ---- K1: in_proj GEMM  (BLx64) @ (64x322) -> g_zx ----
__global__ __launch_bounds__(256) void k_inproj(const float* __restrict__ xext, int sel,
                                                const float* __restrict__ Win) {
  __shared__ float xs[64][64];
  const float* __restrict__ X = (sel==0) ? xext : (sel==1 ? g_ping0 : g_ping1);
  const int row0 = blockIdx.x * 64;
  const int tid  = threadIdx.x;
#pragma unroll
  for (int j=0;j<16;j++){ int e = tid + j*256; int r = e>>6, c2 = e&63;
    xs[r][c2] = X[(size_t)(row0+r)*DMODEL + c2]; }
  __syncthreads();
  const int c = blockIdx.y*256 + tid;
  if (c < PROJ) {
    float w[64];
#pragma unroll
    for (int k=0;k<64;k++) w[k] = Win[k*PROJ + c];
#pragma unroll 4
    for (int r=0;r<64;r++){
      float acc = 0.f;
#pragma unroll
      for (int k=0;k<64;k++) acc = fmaf(xs[r][k], w[k], acc);
      g_zx[(size_t)(row0+r)*PROJ + c] = acc;
    }
  }
}

// ---- K2: dt softplus + within-chunk cumsum of dt*A ----
__global__ __launch_bounds__(64) void k_dtcum(const float* __restrict__ dt_bias,
                                              const float* __restrict__ A_log) {
  const int bx = blockIdx.x;                 // 16*2*64 = 2048 blocks
  const int b = bx >> 7, h = (bx >> 6) & 1, ch = bx & 63;
  const int lane = threadIdx.x;
  const int t = ch*QC + lane;
  float xv  = g_zx[(size_t)(b*SEQ + t)*PROJ + (DINNER+CONVDIM) + h] + dt_bias[h];
  float dtv = (xv > 20.f) ? xv : log1pf(expf(xv));
  float A   = -expf(A_log[h]);
  float cum = dtv * A;
#pragma unroll
  for (int off=1; off<64; off<<=1){
    float v = __shfl_up(cum, off);
    if (lane >= off) cum += v;
  }
  const int base = (b*NHEADS + h)*SEQ + t;
  g_dt [base] = dtv;
  g_cum[base] = cum;
  if (lane == 63) g_ctot[(b*NHEADS+h)*NCHUNK + ch] = cum;
}

// ---- K3: depthwise causal conv(4) + bias + SiLU on xBC columns ----
__global__ __launch_bounds__(256) void k_conv(const float* __restrict__ conv_w,
                                              const float* __restrict__ conv_b) {
  const int idx = blockIdx.x*256 + threadIdx.x;   // < BL*CONVDIM
  const int c = idx % CONVDIM;
  const int r = idx / CONVDIM;
  const int t = r & (SEQ-1);
  float acc = conv_b[c];
#pragma unroll
  for (int k=0;k<4;k++){
    int tt = t - 3 + k;
    if (tt >= 0) acc = fmaf(conv_w[c*4+k], g_zx[(size_t)(r-3+k)*PROJ + DINNER + c], acc);
  }
  g_xbcc[(size_t)r*CONVDIM + c] = acc / (1.f + expf(-acc));
}

// ---- K4 (MFMA): per-(b,h,chunk): G=(C B^T)*mask, Y_intra=G@X, S=chunk state ----
// Layouts (verified m89/m120): A[m=lane&15][k=quad*8+j], B[k=quad*8+j][n=lane&15],
// C/D: col=lane&15, row=quad*4+reg.
__global__ __launch_bounds__(256) void k_chunkA() {
  __shared__ unsigned short Xt [64][72];   // X^T: Xt[p][s]   (pad->144B rows, b128-aligned)
  __shared__ unsigned short Gsh[64][72];   // masked G[t][s]
  __shared__ unsigned short Bt [32][72];   // (ew*B)^T: Bt[n][s]
  __shared__ unsigned short Bsh[64][40];   // B[s][n]
  __shared__ unsigned short Csh[64][40];   // C[t][n]
  __shared__ float cuml[QC], dtl[QC];
  const int bx = blockIdx.x; const int b = bx>>7, h=(bx>>6)&1, ch=bx&63;
  const int tid = threadIdx.x;
  const size_t row0 = (size_t)b*SEQ + (size_t)ch*QC;
  const int cbase = (b*NHEADS+h)*SEQ + ch*QC;
  const float cum_last = g_cum[cbase + 63];
  // stage X (bf16, transposed)
#pragma unroll
  for (int j=0;j<4;j++){
    int e = tid + j*256; int s = e>>4, q = e&15;
    float4 v = *(const float4*)&g_xbcc[(row0+s)*CONVDIM + h*HEADDIM + q*4];
    Xt[q*4+0][s]=f2b(v.x); Xt[q*4+1][s]=f2b(v.y); Xt[q*4+2][s]=f2b(v.z); Xt[q*4+3][s]=f2b(v.w);
  }
  // stage B (row-major + ew-weighted transpose) and C (row-major)
#pragma unroll
  for (int j=0;j<4;j++){
    int e = tid + j*256; int s = e>>4, q = e&15;
    float4 v = *(const float4*)&g_xbcc[(row0+s)*CONVDIM + DINNER + q*4];
    if (q < 8){
      int n0 = q*4;
      Bsh[s][n0+0]=f2b(v.x); Bsh[s][n0+1]=f2b(v.y); Bsh[s][n0+2]=f2b(v.z); Bsh[s][n0+3]=f2b(v.w);
      float ew = expf(cum_last - g_cum[cbase+s]) * g_dt[cbase+s];
      Bt[n0+0][s]=f2b(v.x*ew); Bt[n0+1][s]=f2b(v.y*ew); Bt[n0+2][s]=f2b(v.z*ew); Bt[n0+3][s]=f2b(v.w*ew);
    } else {
      int n0 = (q-8)*4;
      Csh[s][n0+0]=f2b(v.x); Csh[s][n0+1]=f2b(v.y); Csh[s][n0+2]=f2b(v.z); Csh[s][n0+3]=f2b(v.w);
    }
  }
  if (tid < QC){ cuml[tid] = g_cum[cbase+tid]; dtl[tid] = g_dt[cbase+tid]; }
  __syncthreads();
  const int w = tid>>6, l = tid&63, lane15 = l&15, quad = l>>4;
  // --- G = C·B^T (K=32, one MFMA per 16x16 tile), then mask+decay, store bf16 ---
  short8 afr = *(const short8*)&Csh[16*w + lane15][quad*8];
  f32x4 gacc[4];
#pragma unroll
  for (int tn=0;tn<4;tn++){
    short8 bfr = *(const short8*)&Bsh[16*tn + lane15][quad*8];
    f32x4 z = {0.f,0.f,0.f,0.f};
    gacc[tn] = __builtin_amdgcn_mfma_f32_16x16x32_bf16(afr, bfr, z, 0, 0, 0);
  }
#pragma unroll
  for (int tn=0;tn<4;tn++){
    int s = 16*tn + lane15;
    float cs = cuml[s], ds = dtl[s];
#pragma unroll
    for (int r=0;r<4;r++){
      int t = 16*w + quad*4 + r;
      float g = 0.f;
      if (s <= t) g = expf(cuml[t]-cs) * ds * gacc[tn][r];
      Gsh[t][s] = f2b(g);
    }
  }
  __syncthreads();
  // --- Y = G·X (K=64 -> 2 MFMAs per tile), direct global store ---
#pragma unroll
  for (int tn=0;tn<4;tn++){
    f32x4 acc = {0.f,0.f,0.f,0.f};
#pragma unroll
    for (int ks=0;ks<2;ks++){
      short8 a  = *(const short8*)&Gsh[16*w  + lane15][quad*8 + 32*ks];
      short8 bb = *(const short8*)&Xt [16*tn + lane15][quad*8 + 32*ks];
      acc = __builtin_amdgcn_mfma_f32_16x16x32_bf16(a, bb, acc, 0, 0, 0);
    }
    int p = 16*tn + lane15;
#pragma unroll
    for (int r=0;r<4;r++){
      int t = 16*w + quad*4 + r;
      g_y[(row0+t)*DINNER + h*HEADDIM + p] = acc[r];
    }
  }
  // --- S = (ew∘B)^T·X : M=32,N=64,K=64; 8 tiles over 4 waves ---
  const size_t sb = (size_t)((b*NHEADS+h)*NCHUNK + ch) * (DSTATE*HEADDIM);
  const int tm2 = w & 1, tnb = (w>>1)*2;
#pragma unroll
  for (int tt=0;tt<2;tt++){
    int tn2 = tnb + tt;
    f32x4 acc = {0.f,0.f,0.f,0.f};
#pragma unroll
    for (int ks=0;ks<2;ks++){
      short8 a  = *(const short8*)&Bt[16*tm2 + lane15][quad*8 + 32*ks];
      short8 bb = *(const short8*)&Xt[16*tn2 + lane15][quad*8 + 32*ks];
      acc = __builtin_amdgcn_mfma_f32_16x16x32_bf16(a, bb, acc, 0, 0, 0);
    }
    int p = 16*tn2 + lane15;
#pragma unroll
    for (int r=0;r<4;r++){
      int n = 16*tm2 + quad*4 + r;
      g_S[sb + n*HEADDIM + p] = acc[r];
    }
  }
}

// ---- K5: sequential-over-chunks state scan (parallel over b,h,n,p) ----
__global__ __launch_bounds__(256) void k_chunkScan() {
  const int idx = blockIdx.x*256 + threadIdx.x;   // < 65536
  const int np = idx & 2047;
  const int bh = idx >> 11;
  float h = 0.f;
  const size_t base = (size_t)bh*NCHUNK*2048 + np;
#pragma unroll 1
  for (int k=0;k<NCHUNK;k++){
    g_H[base + (size_t)k*2048] = h;                 // state at START of chunk k
    h = h*expf(g_ctot[bh*NCHUNK+k]) + g_S[base + (size_t)k*2048];
  }
}

// ---- K6: add inter-chunk output + D*x, then gate with silu(z) ----
__global__ __launch_bounds__(256) void k_chunkC(const float* __restrict__ Dp) {
  __shared__ float H2[NHEADS][DSTATE*HEADDIM];   // 16 KB
  __shared__ float Cl[QC][DSTATE+1];
  __shared__ float cum2[NHEADS][QC];
  const int bx = blockIdx.x; const int b = bx>>6, ch = bx&63;
  const int tid = threadIdx.x;
  const size_t row0 = (size_t)b*SEQ + (size_t)ch*QC;
#pragma unroll
  for (int j=0;j<16;j++){ int e=tid+j*256; int h_=e>>11, rem=e&2047;
    H2[h_][rem] = g_H[(size_t)((b*NHEADS+h_)*NCHUNK + ch)*2048 + rem]; }
#pragma unroll
  for (int j=0;j<8;j++){ int e=tid+j*256; int s=e>>5, n=e&31;
    Cl[s][n] = g_xbcc[(row0+s)*CONVDIM + DINNER + DSTATE + n]; }
  if (tid < 128){ int h_=tid>>6, s=tid&63;
    cum2[h_][s] = g_cum[(b*NHEADS+h_)*SEQ + ch*QC + s]; }
  __syncthreads();
  const float dp0 = Dp[0], dp1 = Dp[1];
#pragma unroll 1
  for (int e=tid; e<QC*DINNER; e+=256){
    int tq = e>>7, hp = e&127;
    int h_ = hp>>6, p = hp&63;
    size_t row = row0 + tq;
    float acc = 0.f;
#pragma unroll
    for (int n=0;n<DSTATE;n++) acc = fmaf(Cl[tq][n], H2[h_][n*64+p], acc);
    float xval = g_xbcc[row*CONVDIM + hp];
    float yv = g_y[row*DINNER + hp] + expf(cum2[h_][tq])*acc + (h_?dp1:dp0)*xval;
    float zv = g_zx[row*PROJ + hp];
    yv *= zv / (1.f + expf(-zv));
    g_y[row*DINNER + hp] = yv;
  }
}

// ---- K7: RMSNorm + out GEMM (128->64); 16 rows per block ----
__global__ __launch_bounds__(256) void k_outproj(const float* __restrict__ normw,
                                                 const float* __restrict__ Wout,
                                                 float* __restrict__ dout, int dsel) {
  __shared__ float Wl[DINNER*DMODEL];  // 32 KB
  __shared__ float yn[16][DINNER];     // 8 KB
  float* __restrict__ out = (dsel==0) ? g_ping0 : (dsel==1 ? g_ping1 : dout);
  const int tid = threadIdx.x;
#pragma unroll
  for (int j=0;j<32;j++){ int e=tid+j*256; Wl[e] = Wout[e]; }
  const int wave = tid>>6, lane = tid&63;
  const size_t row0 = (size_t)blockIdx.x*16;
#pragma unroll
  for (int rr=0;rr<4;rr++){
    int ri = wave*4 + rr;
    const float* __restrict__ yr = g_y + (row0+ri)*DINNER;
    float v0 = yr[lane], v1 = yr[lane+64];
    float ss = v0*v0 + v1*v1;
#pragma unroll
    for (int off=32; off>=1; off>>=1) ss += __shfl_xor(ss, off);
    float sc = rsqrtf(ss*(1.f/128.f) + 1e-5f);
    yn[ri][lane]    = v0*sc*normw[lane];
    yn[ri][lane+64] = v1*sc*normw[lane+64];
  }
  __syncthreads();
#pragma unroll
  for (int rr=0;rr<4;rr++){
    int ri = wave*4 + rr;
    float acc = 0.f;
#pragma unroll 4
    for (int i=0;i<DINNER;i++) acc = fmaf(yn[ri][i], Wl[i*64+lane], acc);
    out[(row0+ri)*DMODEL + lane] = acc;
  }
}

extern "C" void kernel_launch(void* const* d_in, const int* in_sizes, int n_in,
                              void* d_out, int out_size, void* d_ws, size_t ws_size,
                              hipStream_t stream) {
  (void)in_sizes; (void)n_in; (void)d_ws; (void)ws_size; (void)out_size;
  const float* x       = (const float*)d_in[0];
  const float* Win     = (const float*)d_in[1];
  const float* conv_w  = (const float*)d_in[2];
  const float* conv_b  = (const float*)d_in[3];
  const float* dt_bias = (const float*)d_in[4];
  const float* A_log   = (const float*)d_in[5];
  const float* Dp      = (const float*)d_in[6];
  const float* norm_w  = (const float*)d_in[7];
  const float* Wout    = (const float*)d_in[8];

  for (int layer = 0; layer < 8; ++layer) {
    const int insel = (layer==0) ? 0 : ((((layer-1)&1)==0) ? 1 : 2);
    const int dsel  = (layer==7) ? 2 : ((layer&1)==0 ? 0 : 1);

    k_inproj<<<dim3(BL/64, 2), 256, 0, stream>>>(x, insel, Win + (size_t)layer*DMODEL*PROJ);
    k_dtcum<<<BATCH*NHEADS*NCHUNK, 64, 0, stream>>>(dt_bias + layer*NHEADS, A_log + layer*NHEADS);
    k_conv<<<(BL*CONVDIM)/256, 256, 0, stream>>>(conv_w + (size_t)layer*CONVDIM*4, conv_b + (size_t)layer*CONVDIM);
    k_chunkA<<<BATCH*NHEADS*NCHUNK, 256, 0, stream>>>();
    k_chunkScan<<<(BATCH*NHEADS*DSTATE*HEADDIM)/256, 256, 0, stream>>>();
    k_chunkC<<<BATCH*NCHUNK, 256, 0, stream>>>(Dp + layer*NHEADS);
    k_outproj<<<BL/16, 256, 0, stream>>>(norm_w + layer*DINNER, Wout + (size_t)layer*DINNER*DMODEL,
                                         (float*)d_out, dsel);
  }
}

// Round 4
// 1642.691 us; speedup vs baseline: 2.2623x; 1.5489x over previous
//
#include <hip/hip_runtime.h>
#include <math.h>

// ---- problem constants ----
#define BATCH   16
#define SEQ     4096
#define DMODEL  64
#define DINNER  128
#define DSTATE  32
#define NHEADS  2
#define HEADDIM 64
#define CONVDIM 192            // DINNER + 2*DSTATE
#define PROJ    322            // 2*DINNER + 2*DSTATE + NHEADS
#define QC      64             // chunk length for SSD scan
#define NCHUNK  (SEQ/QC)       // 64
#define BL      (BATCH*SEQ)    // 65536 rows
#define NPAD    336            // PROJ padded to 21*16 for MFMA col tiles

typedef __attribute__((ext_vector_type(8))) short short8;   // 8 bf16 (4 VGPRs)
typedef __attribute__((ext_vector_type(4))) float f32x4;    // MFMA C/D

__device__ inline unsigned short f2b(float f){
  union { float f; unsigned u; } v; v.f = f;
  unsigned r = v.u + 0x7FFF + ((v.u >> 16) & 1);   // round-to-nearest-even
  return (unsigned short)(r >> 16);
}
__device__ inline float b2f(unsigned short s){
  union { unsigned u; float f; } v; v.u = ((unsigned)s) << 16; return v.f;
}
// hi/lo split: x ~= hi + lo, residual ~2^-18 * x
__device__ inline void split2(float x, unsigned short& h, unsigned short& l){
  unsigned short hh = f2b(x);
  h = hh;
  l = f2b(x - b2f(hh));
}

// ---- static device scratch ----
__device__ float g_zx  [(size_t)BL*PROJ];      // in_proj output (z | xBC | dt_raw)
__device__ float g_xbcc[(size_t)BL*CONVDIM];   // conv+silu output (x | B | C)
__device__ float g_dt  [BATCH*NHEADS*SEQ];     // softplus(dt) (fp32 path)
__device__ float g_cum [BATCH*NHEADS*SEQ];     // within-chunk inclusive cumsum of dt*A
__device__ float g_ctot[BATCH*NHEADS*NCHUNK];  // per-chunk total log-decay
__device__ float g_S   [BATCH*NHEADS*NCHUNK*DSTATE*HEADDIM];
__device__ float g_H   [BATCH*NHEADS*NCHUNK*DSTATE*HEADDIM];
__device__ float g_y   [(size_t)BL*DINNER];    // intra-chunk y from chunkA
__device__ float g_ping0[(size_t)BL*DMODEL];
__device__ float g_ping1[(size_t)BL*DMODEL];
__device__ unsigned short g_WinTh [8*NPAD*DMODEL];   // [336][64] bf16 hi
__device__ unsigned short g_WinTl [8*NPAD*DMODEL];   // [336][64] bf16 lo
__device__ unsigned short g_WoutTh[8*DMODEL*DINNER]; // [64][128] bf16 hi (normw folded)
__device__ unsigned short g_WoutTl[8*DMODEL*DINNER]; // [64][128] bf16 lo

// ---- K0: prep transposed hi/lo bf16 weights for all layers ----
__global__ __launch_bounds__(256) void k_prep(const float* __restrict__ Win,
                                              const float* __restrict__ Wout,
                                              const float* __restrict__ normw) {
  const int idx = blockIdx.x*256 + threadIdx.x;
  const int NW = 8*NPAD*DMODEL;              // 172032
  if (idx < NW) {
    int layer = idx / (NPAD*DMODEL);
    int rem   = idx - layer*(NPAD*DMODEL);
    int n = rem >> 6, k = rem & 63;
    float v = (n < PROJ) ? Win[(size_t)layer*DMODEL*PROJ + k*PROJ + n] : 0.f;
    split2(v, g_WinTh[idx], g_WinTl[idx]);
  } else {
    int i2 = idx - NW;
    if (i2 < 8*DMODEL*DINNER) {
      int layer = i2 / (DMODEL*DINNER);
      int rem   = i2 - layer*(DMODEL*DINNER);
      int n = rem >> 7, k = rem & 127;
      float v = Wout[(size_t)layer*DINNER*DMODEL + k*DMODEL + n] * normw[layer*DINNER + k];
      split2(v, g_WoutTh[i2], g_WoutTl[i2]);
    }
  }
}

// ---- K1 (MFMA, split-precision): in_proj (BLx64)@(64x322) ; fused fp32 dt+cumsum ----
__global__ __launch_bounds__(256) void k_inproj(const float* __restrict__ xext, int sel,
                                                const unsigned short* __restrict__ WinTh,
                                                const unsigned short* __restrict__ WinTl,
                                                const float* __restrict__ Win,
                                                const float* __restrict__ dt_bias,
                                                const float* __restrict__ A_log) {
  __shared__ unsigned short Xh[64][72];   // bf16 hi, padded (144B rows)
  __shared__ unsigned short Xl[64][72];   // bf16 lo
  const float* __restrict__ X = (sel==0) ? xext : (sel==1 ? g_ping0 : g_ping1);
  const int bx = blockIdx.x;              // 1024: b = bx>>6, ch = bx&63
  const int row0 = bx * 64;
  const int tid = threadIdx.x;
#pragma unroll
  for (int j=0;j<4;j++){
    int e = tid + j*256; int r = e>>4, c4 = (e&15)*4;
    float4 v = *(const float4*)&X[(size_t)(row0+r)*DMODEL + c4];
    split2(v.x, Xh[r][c4+0], Xl[r][c4+0]);
    split2(v.y, Xh[r][c4+1], Xl[r][c4+1]);
    split2(v.z, Xh[r][c4+2], Xl[r][c4+2]);
    split2(v.w, Xh[r][c4+3], Xl[r][c4+3]);
  }
  const int w = tid>>6, l = tid&63, lane15 = l&15, quad = l>>4;
  // fp32 dt path: waves 0/1 recompute dt columns exactly, then softplus+cumsum
  if (w < 2) {
    const int h = w, t = l;
    float acc = 0.f;
    const float* xr = &X[(size_t)(row0+t)*DMODEL];
#pragma unroll
    for (int k=0;k<64;k++) acc = fmaf(xr[k], Win[k*PROJ + (DINNER+CONVDIM) + h], acc);
    float xv = acc + dt_bias[h];
    float dtv = (xv > 20.f) ? xv : log1pf(expf(xv));
    float A = -expf(A_log[h]);
    float cum = dtv * A;
#pragma unroll
    for (int off=1; off<64; off<<=1){
      float v = __shfl_up(cum, off);
      if (t >= off) cum += v;
    }
    const int b = bx>>6, ch = bx&63;
    const int base = (b*NHEADS + h)*SEQ + ch*QC + t;
    g_dt [base] = dtv;
    g_cum[base] = cum;
    if (t == 63) g_ctot[(b*NHEADS+h)*NCHUNK + ch] = cum;
  }
  __syncthreads();
  // MFMA GEMM, 3-term split: Ah*Bh + Al*Bh + Ah*Bl
  short8 a0h = *(const short8*)&Xh[16*w + lane15][quad*8];
  short8 a1h = *(const short8*)&Xh[16*w + lane15][quad*8 + 32];
  short8 a0l = *(const short8*)&Xl[16*w + lane15][quad*8];
  short8 a1l = *(const short8*)&Xl[16*w + lane15][quad*8 + 32];
#pragma unroll 3
  for (int t=0;t<21;t++){
    const unsigned short* bph = &WinTh[(16*t + lane15)*64 + quad*8];
    const unsigned short* bpl = &WinTl[(16*t + lane15)*64 + quad*8];
    short8 b0h = *(const short8*)bph;
    short8 b1h = *(const short8*)(bph + 32);
    short8 b0l = *(const short8*)bpl;
    short8 b1l = *(const short8*)(bpl + 32);
    f32x4 acc = {0.f,0.f,0.f,0.f};
    acc = __builtin_amdgcn_mfma_f32_16x16x32_bf16(a0h, b0h, acc, 0, 0, 0);
    acc = __builtin_amdgcn_mfma_f32_16x16x32_bf16(a1h, b1h, acc, 0, 0, 0);
    acc = __builtin_amdgcn_mfma_f32_16x16x32_bf16(a0l, b0h, acc, 0, 0, 0);
    acc = __builtin_amdgcn_mfma_f32_16x16x32_bf16(a1l, b1h, acc, 0, 0, 0);
    acc = __builtin_amdgcn_mfma_f32_16x16x32_bf16(a0h, b0l, acc, 0, 0, 0);
    acc = __builtin_amdgcn_mfma_f32_16x16x32_bf16(a1h, b1l, acc, 0, 0, 0);
    int n = 16*t + lane15;
    if (n < PROJ){
#pragma unroll
      for (int r=0;r<4;r++)
        g_zx[(size_t)(row0 + 16*w + quad*4 + r)*PROJ + n] = acc[r];
    }
  }
}

// ---- K3: tiled depthwise causal conv(4) + bias + SiLU ----
__global__ __launch_bounds__(192) void k_conv(const float* __restrict__ conv_w,
                                              const float* __restrict__ conv_b) {
  __shared__ float zs[67][CONVDIM];   // 51.5 KB
  __shared__ float wsh[CONVDIM][4];
  __shared__ float bsh[CONVDIM];
  const int bx = blockIdx.x; const int b = bx>>6, ch = bx&63;
  const int tid = threadIdx.x;
#pragma unroll 1
  for (int e=tid; e<67*96; e+=192){
    int i = e/96, c2 = e-(e/96)*96;
    int tt = ch*64 - 3 + i;
    float2 v = make_float2(0.f,0.f);
    if (tt >= 0) v = *(const float2*)&g_zx[(size_t)(b*SEQ+tt)*PROJ + DINNER + 2*c2];
    *(float2*)&zs[i][2*c2] = v;
  }
  if (tid < CONVDIM){
    bsh[tid] = conv_b[tid];
#pragma unroll
    for (int k=0;k<4;k++) wsh[tid][k] = conv_w[tid*4+k];
  }
  __syncthreads();
  const int c = tid;
  float w0=wsh[c][0], w1=wsh[c][1], w2=wsh[c][2], w3=wsh[c][3], bb=bsh[c];
  float v0=zs[0][c], v1=zs[1][c], v2=zs[2][c];
  const size_t row0 = (size_t)b*SEQ + (size_t)ch*64;
#pragma unroll 4
  for (int t=0;t<64;t++){
    float v3 = zs[t+3][c];
    float acc = fmaf(w0,v0, fmaf(w1,v1, fmaf(w2,v2, fmaf(w3,v3, bb))));
    g_xbcc[(row0+t)*CONVDIM + c] = acc / (1.f + expf(-acc));
    v0=v1; v1=v2; v2=v3;
  }
}

// ---- K4 (MFMA): per-(b,h,chunk): G=(C B^T)*mask, Y_intra=G@X, S=chunk state ----
// (unchanged from the R2 version that passed at 3.9e-3)
__global__ __launch_bounds__(256) void k_chunkA() {
  __shared__ unsigned short Xt [64][72];   // X^T
  __shared__ unsigned short Gsh[64][72];   // masked G[t][s]
  __shared__ unsigned short Bt [32][72];   // (ew*B)^T
  __shared__ unsigned short Bsh[64][40];   // B[s][n]
  __shared__ unsigned short Csh[64][40];   // C[t][n]
  __shared__ float cuml[QC], dtl[QC];
  const int bx = blockIdx.x; const int b = bx>>7, h=(bx>>6)&1, ch=bx&63;
  const int tid = threadIdx.x;
  const size_t row0 = (size_t)b*SEQ + (size_t)ch*QC;
  const int cbase = (b*NHEADS+h)*SEQ + ch*QC;
  const float cum_last = g_cum[cbase + 63];
#pragma unroll
  for (int j=0;j<4;j++){
    int e = tid + j*256; int s = e>>4, q = e&15;
    float4 v = *(const float4*)&g_xbcc[(row0+s)*CONVDIM + h*HEADDIM + q*4];
    Xt[q*4+0][s]=f2b(v.x); Xt[q*4+1][s]=f2b(v.y); Xt[q*4+2][s]=f2b(v.z); Xt[q*4+3][s]=f2b(v.w);
  }
#pragma unroll
  for (int j=0;j<4;j++){
    int e = tid + j*256; int s = e>>4, q = e&15;
    float4 v = *(const float4*)&g_xbcc[(row0+s)*CONVDIM + DINNER + q*4];
    if (q < 8){
      int n0 = q*4;
      Bsh[s][n0+0]=f2b(v.x); Bsh[s][n0+1]=f2b(v.y); Bsh[s][n0+2]=f2b(v.z); Bsh[s][n0+3]=f2b(v.w);
      float ew = expf(cum_last - g_cum[cbase+s]) * g_dt[cbase+s];
      Bt[n0+0][s]=f2b(v.x*ew); Bt[n0+1][s]=f2b(v.y*ew); Bt[n0+2][s]=f2b(v.z*ew); Bt[n0+3][s]=f2b(v.w*ew);
    } else {
      int n0 = (q-8)*4;
      Csh[s][n0+0]=f2b(v.x); Csh[s][n0+1]=f2b(v.y); Csh[s][n0+2]=f2b(v.z); Csh[s][n0+3]=f2b(v.w);
    }
  }
  if (tid < QC){ cuml[tid] = g_cum[cbase+tid]; dtl[tid] = g_dt[cbase+tid]; }
  __syncthreads();
  const int w = tid>>6, l = tid&63, lane15 = l&15, quad = l>>4;
  short8 afr = *(const short8*)&Csh[16*w + lane15][quad*8];
  f32x4 gacc[4];
#pragma unroll
  for (int tn=0;tn<4;tn++){
    short8 bfr = *(const short8*)&Bsh[16*tn + lane15][quad*8];
    f32x4 z = {0.f,0.f,0.f,0.f};
    gacc[tn] = __builtin_amdgcn_mfma_f32_16x16x32_bf16(afr, bfr, z, 0, 0, 0);
  }
#pragma unroll
  for (int tn=0;tn<4;tn++){
    int s = 16*tn + lane15;
    float cs = cuml[s], ds = dtl[s];
#pragma unroll
    for (int r=0;r<4;r++){
      int t = 16*w + quad*4 + r;
      float g = 0.f;
      if (s <= t) g = expf(cuml[t]-cs) * ds * gacc[tn][r];
      Gsh[t][s] = f2b(g);
    }
  }
  __syncthreads();
#pragma unroll
  for (int tn=0;tn<4;tn++){
    f32x4 acc = {0.f,0.f,0.f,0.f};
#pragma unroll
    for (int ks=0;ks<2;ks++){
      short8 a  = *(const short8*)&Gsh[16*w  + lane15][quad*8 + 32*ks];
      short8 bb = *(const short8*)&Xt [16*tn + lane15][quad*8 + 32*ks];
      acc = __builtin_amdgcn_mfma_f32_16x16x32_bf16(a, bb, acc, 0, 0, 0);
    }
    int p = 16*tn + lane15;
#pragma unroll
    for (int r=0;r<4;r++){
      int t = 16*w + quad*4 + r;
      g_y[(row0+t)*DINNER + h*HEADDIM + p] = acc[r];
    }
  }
  const size_t sb = (size_t)((b*NHEADS+h)*NCHUNK + ch) * (DSTATE*HEADDIM);
  const int tm2 = w & 1, tnb = (w>>1)*2;
#pragma unroll
  for (int tt=0;tt<2;tt++){
    int tn2 = tnb + tt;
    f32x4 acc = {0.f,0.f,0.f,0.f};
#pragma unroll
    for (int ks=0;ks<2;ks++){
      short8 a  = *(const short8*)&Bt[16*tm2 + lane15][quad*8 + 32*ks];
      short8 bb = *(const short8*)&Xt[16*tn2 + lane15][quad*8 + 32*ks];
      acc = __builtin_amdgcn_mfma_f32_16x16x32_bf16(a, bb, acc, 0, 0, 0);
    }
    int p = 16*tn2 + lane15;
#pragma unroll
    for (int r=0;r<4;r++){
      int n = 16*tm2 + quad*4 + r;
      g_S[sb + n*HEADDIM + p] = acc[r];
    }
  }
}

// ---- K5: sequential-over-chunks state scan ----
__global__ __launch_bounds__(256) void k_chunkScan() {
  const int idx = blockIdx.x*256 + threadIdx.x;
  const int np = idx & 2047;
  const int bh = idx >> 11;
  float h = 0.f;
  const size_t base = (size_t)bh*NCHUNK*2048 + np;
#pragma unroll 1
  for (int k=0;k<NCHUNK;k++){
    g_H[base + (size_t)k*2048] = h;
    h = h*expf(g_ctot[bh*NCHUNK+k]) + g_S[base + (size_t)k*2048];
  }
}

// ---- K6 (fused): inter-chunk y + D*x + gate + RMSNorm + split-MFMA out_proj ----
__global__ __launch_bounds__(256) void k_fusedC(const float* __restrict__ Dp,
                                                const unsigned short* __restrict__ WoutTh,
                                                const unsigned short* __restrict__ WoutTl,
                                                float* __restrict__ dout, int dsel) {
  __shared__ float H2[NHEADS][DSTATE*HEADDIM];   // 16 KB
  __shared__ float Cl[QC][DSTATE+1];             // 8.4 KB
  __shared__ float cum2[NHEADS][QC];
  __shared__ float yF[64][132];                  // fp32 gated y, padded (528B rows)
  __shared__ float scl[64];
  float* __restrict__ out = (dsel==0) ? g_ping0 : (dsel==1 ? g_ping1 : dout);
  const int bx = blockIdx.x; const int b = bx>>6, ch = bx&63;
  const int tid = threadIdx.x;
  const size_t row0 = (size_t)b*SEQ + (size_t)ch*QC;
#pragma unroll
  for (int j=0;j<16;j++){ int e=tid+j*256; int h_=e>>11, rem=e&2047;
    H2[h_][rem] = g_H[(size_t)((b*NHEADS+h_)*NCHUNK + ch)*2048 + rem]; }
#pragma unroll
  for (int j=0;j<8;j++){ int e=tid+j*256; int s=e>>5, n=e&31;
    Cl[s][n] = g_xbcc[(row0+s)*CONVDIM + DINNER + DSTATE + n]; }
  if (tid < 128){ int h_=tid>>6, s=tid&63;
    cum2[h_][s] = g_cum[(b*NHEADS+h_)*SEQ + ch*QC + s]; }
  __syncthreads();
  const float dp0 = Dp[0], dp1 = Dp[1];
#pragma unroll 1
  for (int e=tid; e<QC*DINNER; e+=256){
    int tq = e>>7, hp = e&127;
    int h_ = hp>>6, p = hp&63;
    size_t row = row0 + tq;
    float acc = 0.f;
#pragma unroll
    for (int n=0;n<DSTATE;n++) acc = fmaf(Cl[tq][n], H2[h_][n*64+p], acc);
    float xval = g_xbcc[row*CONVDIM + hp];
    float yv = g_y[row*DINNER + hp] + expf(cum2[h_][tq])*acc + (h_?dp1:dp0)*xval;
    float zv = g_zx[row*PROJ + hp];
    yv *= zv / (1.f + expf(-zv));
    yF[tq][hp] = yv;
  }
  __syncthreads();
  const int w = tid>>6, l = tid&63, lane15 = l&15, quad = l>>4;
  // RMSNorm scale per row (fp32)
#pragma unroll
  for (int i=0;i<16;i++){
    int row = w*16 + i;
    float v0 = yF[row][l], v1 = yF[row][l+64];
    float ss = v0*v0 + v1*v1;
#pragma unroll
    for (int off=32; off>=1; off>>=1) ss += __shfl_xor(ss, off);
    if (l == 0) scl[row] = rsqrtf(ss*(1.f/128.f) + 1e-5f);
  }
  __syncthreads();
  // out_proj split-MFMA: rows 16w..16w+15 x 64 cols, K=128
  const float sA = scl[16*w + lane15];
  short8 afh[4], afl[4];
#pragma unroll
  for (int ks=0;ks<4;ks++){
    const float* yp = &yF[16*w + lane15][quad*8 + 32*ks];
    float4 u0 = *(const float4*)yp;
    float4 u1 = *(const float4*)(yp+4);
    float vv[8] = {u0.x,u0.y,u0.z,u0.w,u1.x,u1.y,u1.z,u1.w};
#pragma unroll
    for (int j=0;j<8;j++){
      unsigned short hh, ll;
      split2(vv[j]*sA, hh, ll);
      afh[ks][j] = (short)hh; afl[ks][j] = (short)ll;
    }
  }
#pragma unroll
  for (int tc=0;tc<4;tc++){
    f32x4 acc = {0.f,0.f,0.f,0.f};
#pragma unroll
    for (int ks=0;ks<4;ks++){
      const unsigned short* bph = &WoutTh[(16*tc + lane15)*DINNER + quad*8 + 32*ks];
      const unsigned short* bpl = &WoutTl[(16*tc + lane15)*DINNER + quad*8 + 32*ks];
      short8 bh = *(const short8*)bph;
      short8 blo = *(const short8*)bpl;
      acc = __builtin_amdgcn_mfma_f32_16x16x32_bf16(afh[ks], bh,  acc, 0, 0, 0);
      acc = __builtin_amdgcn_mfma_f32_16x16x32_bf16(afl[ks], bh,  acc, 0, 0, 0);
      acc = __builtin_amdgcn_mfma_f32_16x16x32_bf16(afh[ks], blo, acc, 0, 0, 0);
    }
    int n = 16*tc + lane15;
#pragma unroll
    for (int r=0;r<4;r++)
      out[(row0 + 16*w + quad*4 + r)*DMODEL + n] = acc[r];
  }
}

extern "C" void kernel_launch(void* const* d_in, const int* in_sizes, int n_in,
                              void* d_out, int out_size, void* d_ws, size_t ws_size,
                              hipStream_t stream) {
  (void)in_sizes; (void)n_in; (void)d_ws; (void)ws_size; (void)out_size;
  const float* x       = (const float*)d_in[0];
  const float* Win     = (const float*)d_in[1];
  const float* conv_w  = (const float*)d_in[2];
  const float* conv_b  = (const float*)d_in[3];
  const float* dt_bias = (const float*)d_in[4];
  const float* A_log   = (const float*)d_in[5];
  const float* Dp      = (const float*)d_in[6];
  const float* norm_w  = (const float*)d_in[7];
  const float* Wout    = (const float*)d_in[8];

  k_prep<<<(8*(NPAD*DMODEL + DMODEL*DINNER) + 255)/256, 256, 0, stream>>>(Win, Wout, norm_w);

  unsigned short *winTh, *winTl, *woutTh, *woutTl;
  hipGetSymbolAddress((void**)&winTh,  HIP_SYMBOL(g_WinTh));
  hipGetSymbolAddress((void**)&winTl,  HIP_SYMBOL(g_WinTl));
  hipGetSymbolAddress((void**)&woutTh, HIP_SYMBOL(g_WoutTh));
  hipGetSymbolAddress((void**)&woutTl, HIP_SYMBOL(g_WoutTl));

  for (int layer = 0; layer < 8; ++layer) {
    const int insel = (layer==0) ? 0 : ((((layer-1)&1)==0) ? 1 : 2);
    const int dsel  = (layer==7) ? 2 : ((layer&1)==0 ? 0 : 1);

    k_inproj<<<BL/64, 256, 0, stream>>>(x, insel,
                                        winTh + (size_t)layer*NPAD*DMODEL,
                                        winTl + (size_t)layer*NPAD*DMODEL,
                                        Win + (size_t)layer*DMODEL*PROJ,
                                        dt_bias + layer*NHEADS, A_log + layer*NHEADS);
    k_conv<<<BATCH*NCHUNK, 192, 0, stream>>>(conv_w + (size_t)layer*CONVDIM*4,
                                             conv_b + (size_t)layer*CONVDIM);
    k_chunkA<<<BATCH*NHEADS*NCHUNK, 256, 0, stream>>>();
    k_chunkScan<<<(BATCH*NHEADS*DSTATE*HEADDIM)/256, 256, 0, stream>>>();
    k_fusedC<<<BATCH*NCHUNK, 256, 0, stream>>>(Dp + layer*NHEADS,
                                               woutTh + (size_t)layer*DMODEL*DINNER,
                                               woutTl + (size_t)layer*DMODEL*DINNER,
                                               (float*)d_out, dsel);
  }
}